// Round 1
// baseline (261.658 us; speedup 1.0000x reference)
//
#include <hip/hip_runtime.h>
#include <stdint.h>

#define MDIM 1024
#define NDIM 2048
#define KDIM 2048
#define BETAC 0.9f
#define LAMC 1e-4f

typedef __attribute__((ext_vector_type(4))) float f32x4;
typedef __attribute__((ext_vector_type(8))) short s16x8;

typedef __attribute__((address_space(3))) unsigned int as3_u32;
typedef __attribute__((address_space(1))) unsigned int as1_u32;

__device__ __forceinline__ void gload_lds16(const void* g, const void* l) {
  __builtin_amdgcn_global_load_lds((const as1_u32*)(uintptr_t)g,
                                   (as3_u32*)(unsigned int)(uintptr_t)l, 16, 0, 0);
}

__device__ __forceinline__ unsigned short f2bf(float f) {
  union { float f; unsigned u; } x; x.f = f;
  unsigned r = x.u + 0x7fffu + ((x.u >> 16) & 1u);
  return (unsigned short)(r >> 16);
}

// ---------------- transpose + f32->bf16 convert: WT[n][k] = bf16(W[k][n]) ----------------
__global__ __launch_bounds__(256) void transpose_cvt_kernel(const float* __restrict__ W,
                                                            unsigned short* __restrict__ WT) {
  __shared__ float tile[32][33];
  const int tx = threadIdx.x, ty = threadIdx.y;
  const int col = blockIdx.x * 32 + tx;
  const int row0 = blockIdx.y * 32 + ty;
#pragma unroll
  for (int j = 0; j < 32; j += 8)
    tile[ty + j][tx] = W[(size_t)(row0 + j) * NDIM + col];
  __syncthreads();
  const int ocol = blockIdx.y * 32 + tx;
  const int orow0 = blockIdx.x * 32 + ty;
#pragma unroll
  for (int j = 0; j < 32; j += 8)
    WT[(size_t)(orow0 + j) * KDIM + ocol] = f2bf(tile[tx][ty + j]);
}

// ---------------- f32 -> bf16 elementwise ----------------
__global__ __launch_bounds__(256) void cvt_bf16_kernel(const float* __restrict__ in,
                                                       unsigned short* __restrict__ out, int n4) {
  int i = blockIdx.x * blockDim.x + threadIdx.x;
  if (i >= n4) return;
  f32x4 v = ((const f32x4*)in)[i];
  ushort4 o;
  o.x = f2bf(v[0]); o.y = f2bf(v[1]); o.z = f2bf(v[2]); o.w = f2bf(v[3]);
  ((ushort4*)out)[i] = o;
}

// ---------------- GEMM: C = A(bf16 MxK) * BT(bf16 NxK)^T, fused epilogue ----------------
// EPI==0: out[m][n] = acc + bias[n]                       (x_proj)
// EPI==1: out[m][n] = tanh(acc + xproj[m][n]) - z[m][n]   (g)
template <int EPI>
__global__ __launch_bounds__(256) void gemm_kernel(const unsigned short* __restrict__ A,
                                                   const unsigned short* __restrict__ BT,
                                                   const float* __restrict__ xproj,
                                                   const float* __restrict__ z_or_bias,
                                                   float* __restrict__ out) {
  // double-buffered LDS, XOR-swizzled layout (read: idx ^ ((row&7)<<3) in shorts)
  __shared__ short As[2][64 * 64];
  __shared__ short Bs[2][128 * 64];

  const int tid = threadIdx.x;
  const int l = tid & 63;
  const int w = tid >> 6;
  const int wr = w >> 1, wc = w & 1;
  const int row0 = blockIdx.y * 64;
  const int col0 = blockIdx.x * 128;
  const int lrow = l & 15;
  const int lk8 = (l >> 4) * 8;
  const int wuni = (tid & ~63) * 8;  // wave-uniform LDS element base

  f32x4 acc[2][4];
#pragma unroll
  for (int mi = 0; mi < 2; mi++)
#pragma unroll
    for (int ni = 0; ni < 4; ni++) acc[mi][ni] = f32x4{0.f, 0.f, 0.f, 0.f};

  // staging: slot u holds 8 shorts at LDS element u*8; row r=u>>3; source k-chunk pre-swizzled
  auto stage = [&](int k0, int buf) {
#pragma unroll
    for (int p = 0; p < 2; p++) {  // A: 64x64 -> 512 slots
      int u = p * 256 + tid;
      int r = u >> 3;
      int c = ((u & 7) ^ (r & 7)) * 8;
      const unsigned short* src = A + (size_t)(row0 + r) * KDIM + k0 + c;
      const short* dst = &As[buf][p * 2048 + wuni];
      gload_lds16(src, dst);
    }
#pragma unroll
    for (int p = 0; p < 4; p++) {  // B: 128x64 -> 1024 slots
      int u = p * 256 + tid;
      int r = u >> 3;
      int c = ((u & 7) ^ (r & 7)) * 8;
      const unsigned short* src = BT + (size_t)(col0 + r) * KDIM + k0 + c;
      const short* dst = &Bs[buf][p * 2048 + wuni];
      gload_lds16(src, dst);
    }
  };

  constexpr int NT = KDIM / 64;
  stage(0, 0);
  asm volatile("s_waitcnt vmcnt(0)" ::: "memory");
  __syncthreads();

  for (int t = 0; t < NT; ++t) {
    const int cur = t & 1;
    if (t + 1 < NT) stage((t + 1) * 64, cur ^ 1);
#pragma unroll
    for (int ks = 0; ks < 2; ++ks) {
      const int kk = ks * 32 + lk8;
      s16x8 a[2], b[4];
#pragma unroll
      for (int mi = 0; mi < 2; mi++) {
        int rr = wr * 32 + mi * 16 + lrow;
        int sidx = (rr * 64 + kk) ^ ((rr & 7) << 3);
        a[mi] = *(const s16x8*)(&As[cur][sidx]);
      }
#pragma unroll
      for (int ni = 0; ni < 4; ni++) {
        int rr = wc * 64 + ni * 16 + lrow;
        int sidx = (rr * 64 + kk) ^ ((rr & 7) << 3);
        b[ni] = *(const s16x8*)(&Bs[cur][sidx]);
      }
#pragma unroll
      for (int mi = 0; mi < 2; mi++)
#pragma unroll
        for (int ni = 0; ni < 4; ni++)
          acc[mi][ni] = __builtin_amdgcn_mfma_f32_16x16x32_bf16(a[mi], b[ni], acc[mi][ni], 0, 0, 0);
    }
    asm volatile("s_waitcnt vmcnt(0)" ::: "memory");
    __syncthreads();
  }

  // epilogue
#pragma unroll
  for (int mi = 0; mi < 2; mi++) {
#pragma unroll
    for (int ni = 0; ni < 4; ni++) {
      const int col = col0 + wc * 64 + ni * 16 + lrow;
      const int rbase = row0 + wr * 32 + mi * 16 + (l >> 4) * 4;
#pragma unroll
      for (int j = 0; j < 4; j++) {
        const int row = rbase + j;
        const size_t idx = (size_t)row * NDIM + col;
        const float v = acc[mi][ni][j];
        if (EPI == 0) {
          out[idx] = v + z_or_bias[col];
        } else {
          float fz = tanhf(v + xproj[idx]);
          out[idx] = fz - z_or_bias[idx];
        }
      }
    }
  }
}

// ---------------- iteration 0: z1 = 0.9*tanh(x_proj) ----------------
__global__ __launch_bounds__(256) void iter0_kernel(const float* __restrict__ xproj,
                                                    float* __restrict__ z,
                                                    unsigned short* __restrict__ zb, int n4) {
  int i = blockIdx.x * blockDim.x + threadIdx.x;
  if (i >= n4) return;
  f32x4 xp = ((const f32x4*)xproj)[i];
  f32x4 zn;
#pragma unroll
  for (int j = 0; j < 4; j++) zn[j] = BETAC * tanhf(xp[j]);
  ((f32x4*)z)[i] = zn;
  ushort4 o;
  o.x = f2bf(zn[0]); o.y = f2bf(zn[1]); o.z = f2bf(zn[2]); o.w = f2bf(zn[3]);
  ((ushort4*)zb)[i] = o;
}

// ---------------- simple update: z_new = z + 0.9*g ----------------
__global__ __launch_bounds__(256) void simple_update_kernel(const float* __restrict__ z,
                                                            const float* __restrict__ g,
                                                            float* __restrict__ zout,
                                                            unsigned short* __restrict__ zb, int n4) {
  int i = blockIdx.x * blockDim.x + threadIdx.x;
  if (i >= n4) return;
  f32x4 zz = ((const f32x4*)z)[i];
  f32x4 gg = ((const f32x4*)g)[i];
  f32x4 zn;
#pragma unroll
  for (int j = 0; j < 4; j++) zn[j] = zz[j] + BETAC * gg[j];
  ((f32x4*)zout)[i] = zn;
  ushort4 o;
  o.x = f2bf(zn[0]); o.y = f2bf(zn[1]); o.z = f2bf(zn[2]); o.w = f2bf(zn[3]);
  ((ushort4*)zb)[i] = o;
}

// ---------------- per-row gamma = sum(dg*g)/(sum(dg*dg)+lam) ----------------
__global__ __launch_bounds__(256) void gamma_kernel(const float* __restrict__ g,
                                                    const float* __restrict__ gp,
                                                    float* __restrict__ gamma) {
  const int row = blockIdx.x;
  const f32x4* g4 = (const f32x4*)(g + (size_t)row * NDIM);
  const f32x4* p4 = (const f32x4*)(gp + (size_t)row * NDIM);
  float num = 0.f, den = 0.f;
  for (int i = threadIdx.x; i < NDIM / 4; i += 256) {
    f32x4 a = g4[i], b = p4[i];
#pragma unroll
    for (int j = 0; j < 4; j++) {
      float d = a[j] - b[j];
      num += d * a[j];
      den += d * d;
    }
  }
#pragma unroll
  for (int off = 32; off > 0; off >>= 1) {
    num += __shfl_down(num, off);
    den += __shfl_down(den, off);
  }
  __shared__ float sn[4], sd[4];
  if ((threadIdx.x & 63) == 0) { sn[threadIdx.x >> 6] = num; sd[threadIdx.x >> 6] = den; }
  __syncthreads();
  if (threadIdx.x == 0) {
    float N = sn[0] + sn[1] + sn[2] + sn[3];
    float D = sd[0] + sd[1] + sd[2] + sd[3];
    gamma[row] = N / (D + LAMC);
  }
}

// ---------------- anderson update ----------------
__global__ __launch_bounds__(256) void anderson_kernel(const float* __restrict__ z,
                                                       const float* __restrict__ zp,
                                                       const float* __restrict__ g,
                                                       const float* __restrict__ gp,
                                                       const float* __restrict__ gamma,
                                                       float* __restrict__ zout,
                                                       unsigned short* __restrict__ zb, int n4) {
  int i = blockIdx.x * blockDim.x + threadIdx.x;
  if (i >= n4) return;
  const float ga = gamma[i >> 9];  // 512 float4s per row
  f32x4 zz = ((const f32x4*)z)[i];
  f32x4 zpp = ((const f32x4*)zp)[i];
  f32x4 gg = ((const f32x4*)g)[i];
  f32x4 gpp = ((const f32x4*)gp)[i];
  f32x4 zn;
#pragma unroll
  for (int j = 0; j < 4; j++)
    zn[j] = zz[j] + BETAC * gg[j] - ga * ((zz[j] - zpp[j]) + BETAC * (gg[j] - gpp[j]));
  ((f32x4*)zout)[i] = zn;
  if (zb) {
    ushort4 o;
    o.x = f2bf(zn[0]); o.y = f2bf(zn[1]); o.z = f2bf(zn[2]); o.w = f2bf(zn[3]);
    ((ushort4*)zb)[i] = o;
  }
}

extern "C" void kernel_launch(void* const* d_in, const int* in_sizes, int n_in,
                              void* d_out, int out_size, void* d_ws, size_t ws_size,
                              hipStream_t stream) {
  const float* x = (const float*)d_in[0];
  const float* Wz = (const float*)d_in[1];
  const float* Wx = (const float*)d_in[2];
  const float* bias = (const float*)d_in[3];

  const size_t MN = (size_t)MDIM * NDIM;       // 2097152
  const size_t KN = (size_t)KDIM * NDIM;       // 4194304
  char* ws = (char*)d_ws;
  size_t off = 0;
  auto alloc = [&](size_t bytes) -> void* {
    void* p = ws + off;
    off += (bytes + 255) & ~(size_t)255;
    return p;
  };
  unsigned short* WzT = (unsigned short*)alloc(KN * 2);
  unsigned short* WxT = (unsigned short*)alloc(KN * 2);
  unsigned short* xb = (unsigned short*)alloc(MN * 2);
  float* xproj = (float*)alloc(MN * 4);
  float* zA = (float*)alloc(MN * 4);
  float* zB = (float*)alloc(MN * 4);
  float* gA = (float*)alloc(MN * 4);
  float* gB = (float*)alloc(MN * 4);
  unsigned short* zb16 = (unsigned short*)alloc(MN * 2);
  float* gamma = (float*)alloc(MDIM * 4);
  (void)ws_size;

  const int n4 = (int)(MN / 4);
  const dim3 tb(32, 8);
  const dim3 tgrid(NDIM / 32, KDIM / 32);
  const dim3 ggrid(NDIM / 128, MDIM / 64);
  const int ewblocks = n4 / 256;

  transpose_cvt_kernel<<<tgrid, tb, 0, stream>>>(Wz, WzT);
  transpose_cvt_kernel<<<tgrid, tb, 0, stream>>>(Wx, WxT);
  cvt_bf16_kernel<<<ewblocks, 256, 0, stream>>>(x, xb, n4);

  // x_proj = x @ Wx + b
  gemm_kernel<0><<<ggrid, 256, 0, stream>>>(xb, WxT, nullptr, bias, xproj);

  // i = 0 : z1 = 0.9 * tanh(x_proj)
  iter0_kernel<<<ewblocks, 256, 0, stream>>>(xproj, zA, zb16, n4);

  float* zc = zA;   // current z
  float* zp = zB;   // prev z (free buffer initially)
  float* gc = gA;   // g buffer for this iter
  float* gp = gB;   // prev g

  // i = 1 : simple update
  gemm_kernel<1><<<ggrid, 256, 0, stream>>>(zb16, WzT, xproj, zc, gc);
  simple_update_kernel<<<ewblocks, 256, 0, stream>>>(zc, gc, zp, zb16, n4);
  { float* t = zc; zc = zp; zp = t; }
  { float* t = gc; gc = gp; gp = t; }

  // i = 2..5 : anderson updates
  for (int it = 2; it < 6; ++it) {
    gemm_kernel<1><<<ggrid, 256, 0, stream>>>(zb16, WzT, xproj, zc, gc);
    gamma_kernel<<<MDIM, 256, 0, stream>>>(gc, gp, gamma);
    if (it < 5) {
      anderson_kernel<<<ewblocks, 256, 0, stream>>>(zc, zp, gc, gp, gamma, zp, zb16, n4);
      { float* t = zc; zc = zp; zp = t; }
      { float* t = gc; gc = gp; gp = t; }
    } else {
      anderson_kernel<<<ewblocks, 256, 0, stream>>>(zc, zp, gc, gp, gamma, (float*)d_out, nullptr, n4);
    }
  }
}

// Round 2
// 220.429 us; speedup vs baseline: 1.1870x; 1.1870x over previous
//
#include <hip/hip_runtime.h>
#include <stdint.h>

#define MDIM 1024
#define NDIM 2048
#define KDIM 2048
#define BETAC 0.9f
#define LAMC 1e-4f

typedef __attribute__((ext_vector_type(4))) float f32x4;
typedef __attribute__((ext_vector_type(8))) short s16x8;

typedef __attribute__((address_space(3))) unsigned int as3_u32;
typedef __attribute__((address_space(1))) unsigned int as1_u32;

__device__ __forceinline__ void gload_lds16(const void* g, const void* l) {
  __builtin_amdgcn_global_load_lds((const as1_u32*)(uintptr_t)g,
                                   (as3_u32*)(unsigned int)(uintptr_t)l, 16, 0, 0);
}

__device__ __forceinline__ unsigned short f2bf(float f) {
  union { float f; unsigned u; } x; x.f = f;
  unsigned r = x.u + 0x7fffu + ((x.u >> 16) & 1u);
  return (unsigned short)(r >> 16);
}

// ---------------- both weight transposes in one launch: WT[n][k] = bf16(W[k][n]) ----------------
__global__ __launch_bounds__(256) void transpose_cvt2_kernel(const float* __restrict__ Wz,
                                                             const float* __restrict__ Wx,
                                                             unsigned short* __restrict__ WzT,
                                                             unsigned short* __restrict__ WxT) {
  const float* W = blockIdx.z ? Wx : Wz;
  unsigned short* WT = blockIdx.z ? WxT : WzT;
  __shared__ float tile[32][33];
  const int tx = threadIdx.x, ty = threadIdx.y;
  const int col = blockIdx.x * 32 + tx;
  const int row0 = blockIdx.y * 32 + ty;
#pragma unroll
  for (int j = 0; j < 32; j += 8)
    tile[ty + j][tx] = W[(size_t)(row0 + j) * NDIM + col];
  __syncthreads();
  const int ocol = blockIdx.y * 32 + tx;
  const int orow0 = blockIdx.x * 32 + ty;
#pragma unroll
  for (int j = 0; j < 32; j += 8)
    WT[(size_t)(orow0 + j) * KDIM + ocol] = f2bf(tile[tx][ty + j]);
}

// ---------------- f32 -> bf16 elementwise ----------------
__global__ __launch_bounds__(256) void cvt_bf16_kernel(const float* __restrict__ in,
                                                       unsigned short* __restrict__ out, int n4) {
  int i = blockIdx.x * blockDim.x + threadIdx.x;
  if (i >= n4) return;
  f32x4 v = ((const f32x4*)in)[i];
  ushort4 o;
  o.x = f2bf(v[0]); o.y = f2bf(v[1]); o.z = f2bf(v[2]); o.w = f2bf(v[3]);
  ((ushort4*)out)[i] = o;
}

// ---------------- GEMM: C = A(bf16 MxK) * BT(bf16 NxK)^T ----------------
// BM=64 BN=128 BK=128, 256 threads (4 waves, each 32x64), dbuf LDS 96KB, 1 block/CU.
// EPI==0: xproj = acc + bias[n]; z = 0.9*tanh(xproj); zb = bf16(z)       (fused iter0)
// EPI==1: g = tanh(acc + xproj) - z; znew = z + 0.9*g; zb = bf16(znew)   (fused simple update)
// EPI==2: g = tanh(acc + xproj) - z                                      (g for anderson iters)
template <int EPI>
__global__ __launch_bounds__(256) void gemm_kernel(const unsigned short* __restrict__ A,
                                                   const unsigned short* __restrict__ BT,
                                                   const float* __restrict__ xproj,
                                                   const float* __restrict__ zin_or_bias,
                                                   float* __restrict__ gout,
                                                   float* __restrict__ znew,
                                                   unsigned short* __restrict__ zbout) {
  // XOR-swizzled LDS (element idx ^ ((row&7)<<3)), staged via pre-swizzled global source
  __shared__ short As[2][64 * 128];    // 32 KB
  __shared__ short Bs[2][128 * 128];   // 64 KB

  const int tid = threadIdx.x;
  const int l = tid & 63;
  const int w = tid >> 6;
  const int wr = w >> 1, wc = w & 1;
  const int row0 = blockIdx.y * 64;
  const int col0 = blockIdx.x * 128;
  const int lrow = l & 15;
  const int lk8 = (l >> 4) * 8;
  const int wuni = (tid & ~63) * 8;  // wave-uniform LDS element base

  f32x4 acc[2][4];
#pragma unroll
  for (int mi = 0; mi < 2; mi++)
#pragma unroll
    for (int ni = 0; ni < 4; ni++) acc[mi][ni] = f32x4{0.f, 0.f, 0.f, 0.f};

  // stage one BK=128 tile: A 64x128 (1024 slots of 16B), B 128x128 (2048 slots)
  // slot u -> row r = u>>4, col-group g = u&15, source chunk c = (g ^ (r&7))*8
  auto stage = [&](int k0, int buf) {
#pragma unroll
    for (int p = 0; p < 4; p++) {
      int u = p * 256 + tid;
      int r = u >> 4;
      int c = ((u & 15) ^ (r & 7)) * 8;
      const unsigned short* src = A + (size_t)(row0 + r) * KDIM + k0 + c;
      const short* dst = &As[buf][p * 2048 + wuni];
      gload_lds16(src, dst);
    }
#pragma unroll
    for (int p = 0; p < 8; p++) {
      int u = p * 256 + tid;
      int r = u >> 4;
      int c = ((u & 15) ^ (r & 7)) * 8;
      const unsigned short* src = BT + (size_t)(col0 + r) * KDIM + k0 + c;
      const short* dst = &Bs[buf][p * 2048 + wuni];
      gload_lds16(src, dst);
    }
  };

  constexpr int NT = KDIM / 128;
  stage(0, 0);
  asm volatile("s_waitcnt vmcnt(0)" ::: "memory");
  __syncthreads();

  for (int t = 0; t < NT; ++t) {
    const int cur = t & 1;
    if (t + 1 < NT) stage((t + 1) * 128, cur ^ 1);
#pragma unroll
    for (int ks = 0; ks < 4; ++ks) {
      const int kk = ks * 32 + lk8;
      s16x8 a[2], b[4];
#pragma unroll
      for (int mi = 0; mi < 2; mi++) {
        int rr = wr * 32 + mi * 16 + lrow;
        int sidx = (rr * 128 + kk) ^ ((rr & 7) << 3);
        a[mi] = *(const s16x8*)(&As[cur][sidx]);
      }
#pragma unroll
      for (int ni = 0; ni < 4; ni++) {
        int rr = wc * 64 + ni * 16 + lrow;
        int sidx = (rr * 128 + kk) ^ ((rr & 7) << 3);
        b[ni] = *(const s16x8*)(&Bs[cur][sidx]);
      }
#pragma unroll
      for (int mi = 0; mi < 2; mi++)
#pragma unroll
        for (int ni = 0; ni < 4; ni++)
          acc[mi][ni] = __builtin_amdgcn_mfma_f32_16x16x32_bf16(a[mi], b[ni], acc[mi][ni], 0, 0, 0);
    }
    asm volatile("s_waitcnt vmcnt(0)" ::: "memory");
    __syncthreads();
  }

  // fused epilogue
#pragma unroll
  for (int mi = 0; mi < 2; mi++) {
#pragma unroll
    for (int ni = 0; ni < 4; ni++) {
      const int col = col0 + wc * 64 + ni * 16 + lrow;
      const int rbase = row0 + wr * 32 + mi * 16 + (l >> 4) * 4;
#pragma unroll
      for (int j = 0; j < 4; j++) {
        const int row = rbase + j;
        const size_t idx = (size_t)row * NDIM + col;
        const float v = acc[mi][ni][j];
        if (EPI == 0) {
          const float xp = v + zin_or_bias[col];
          gout[idx] = xp;                       // xproj
          const float z1 = BETAC * tanhf(xp);
          znew[idx] = z1;
          zbout[idx] = f2bf(z1);
        } else {
          const float z = zin_or_bias[idx];
          const float g = tanhf(v + xproj[idx]) - z;
          gout[idx] = g;
          if (EPI == 1) {
            const float zn = z + BETAC * g;
            znew[idx] = zn;
            zbout[idx] = f2bf(zn);
          }
        }
      }
    }
  }
}

// ---------------- per-row gamma = sum(dg*g)/(sum(dg*dg)+lam) ----------------
__global__ __launch_bounds__(256) void gamma_kernel(const float* __restrict__ g,
                                                    const float* __restrict__ gp,
                                                    float* __restrict__ gamma) {
  const int row = blockIdx.x;
  const f32x4* g4 = (const f32x4*)(g + (size_t)row * NDIM);
  const f32x4* p4 = (const f32x4*)(gp + (size_t)row * NDIM);
  float num = 0.f, den = 0.f;
  for (int i = threadIdx.x; i < NDIM / 4; i += 256) {
    f32x4 a = g4[i], b = p4[i];
#pragma unroll
    for (int j = 0; j < 4; j++) {
      float d = a[j] - b[j];
      num += d * a[j];
      den += d * d;
    }
  }
#pragma unroll
  for (int off = 32; off > 0; off >>= 1) {
    num += __shfl_down(num, off);
    den += __shfl_down(den, off);
  }
  __shared__ float sn[4], sd[4];
  if ((threadIdx.x & 63) == 0) { sn[threadIdx.x >> 6] = num; sd[threadIdx.x >> 6] = den; }
  __syncthreads();
  if (threadIdx.x == 0) {
    float N = sn[0] + sn[1] + sn[2] + sn[3];
    float D = sd[0] + sd[1] + sd[2] + sd[3];
    gamma[row] = N / (D + LAMC);
  }
}

// ---------------- anderson update ----------------
__global__ __launch_bounds__(256) void anderson_kernel(const float* __restrict__ z,
                                                       const float* __restrict__ zp,
                                                       const float* __restrict__ g,
                                                       const float* __restrict__ gp,
                                                       const float* __restrict__ gamma,
                                                       float* __restrict__ zout,
                                                       unsigned short* __restrict__ zb, int n4) {
  int i = blockIdx.x * blockDim.x + threadIdx.x;
  if (i >= n4) return;
  const float ga = gamma[i >> 9];  // 512 float4s per row
  f32x4 zz = ((const f32x4*)z)[i];
  f32x4 zpp = ((const f32x4*)zp)[i];
  f32x4 gg = ((const f32x4*)g)[i];
  f32x4 gpp = ((const f32x4*)gp)[i];
  f32x4 zn;
#pragma unroll
  for (int j = 0; j < 4; j++)
    zn[j] = zz[j] + BETAC * gg[j] - ga * ((zz[j] - zpp[j]) + BETAC * (gg[j] - gpp[j]));
  ((f32x4*)zout)[i] = zn;
  if (zb) {
    ushort4 o;
    o.x = f2bf(zn[0]); o.y = f2bf(zn[1]); o.z = f2bf(zn[2]); o.w = f2bf(zn[3]);
    ((ushort4*)zb)[i] = o;
  }
}

extern "C" void kernel_launch(void* const* d_in, const int* in_sizes, int n_in,
                              void* d_out, int out_size, void* d_ws, size_t ws_size,
                              hipStream_t stream) {
  const float* x = (const float*)d_in[0];
  const float* Wz = (const float*)d_in[1];
  const float* Wx = (const float*)d_in[2];
  const float* bias = (const float*)d_in[3];

  const size_t MN = (size_t)MDIM * NDIM;
  const size_t KN = (size_t)KDIM * NDIM;
  char* ws = (char*)d_ws;
  size_t off = 0;
  auto alloc = [&](size_t bytes) -> void* {
    void* p = ws + off;
    off += (bytes + 255) & ~(size_t)255;
    return p;
  };
  unsigned short* WzT = (unsigned short*)alloc(KN * 2);
  unsigned short* WxT = (unsigned short*)alloc(KN * 2);
  unsigned short* xb = (unsigned short*)alloc(MN * 2);
  float* xproj = (float*)alloc(MN * 4);
  float* zA = (float*)alloc(MN * 4);
  float* zB = (float*)alloc(MN * 4);
  float* gA = (float*)alloc(MN * 4);
  float* gB = (float*)alloc(MN * 4);
  unsigned short* zb16 = (unsigned short*)alloc(MN * 2);
  float* gamma = (float*)alloc(MDIM * 4);
  (void)ws_size;

  const int n4 = (int)(MN / 4);
  const dim3 tb(32, 8);
  const dim3 tgrid(NDIM / 32, KDIM / 32, 2);
  const dim3 ggrid(NDIM / 128, MDIM / 64);
  const int ewblocks = n4 / 256;

  transpose_cvt2_kernel<<<tgrid, tb, 0, stream>>>(Wz, Wx, WzT, WxT);
  cvt_bf16_kernel<<<ewblocks, 256, 0, stream>>>(x, xb, n4);

  // x_proj = x @ Wx + b ; fused iter0: z1 = 0.9*tanh(x_proj)
  gemm_kernel<0><<<ggrid, 256, 0, stream>>>(xb, WxT, nullptr, bias, xproj, zA, zb16);

  float* zc = zA;   // current z (z1)
  float* zp = zB;
  float* gc = gA;
  float* gp = gB;

  // i = 1 : g1 + fused simple update -> z2
  gemm_kernel<1><<<ggrid, 256, 0, stream>>>(zb16, WzT, xproj, zc, gc, zp, zb16);
  { float* t = zc; zc = zp; zp = t; }  // zc=z2, zp=z1
  { float* t = gc; gc = gp; gp = t; }  // gp=g1

  // i = 2..5 : anderson updates
  for (int it = 2; it < 6; ++it) {
    gemm_kernel<2><<<ggrid, 256, 0, stream>>>(zb16, WzT, xproj, zc, gc, nullptr, nullptr);
    gamma_kernel<<<MDIM, 256, 0, stream>>>(gc, gp, gamma);
    if (it < 5) {
      anderson_kernel<<<ewblocks, 256, 0, stream>>>(zc, zp, gc, gp, gamma, zp, zb16, n4);
      { float* t = zc; zc = zp; zp = t; }
      { float* t = gc; gc = gp; gp = t; }
    } else {
      anderson_kernel<<<ewblocks, 256, 0, stream>>>(zc, zp, gc, gp, gamma, (float*)d_out, nullptr, n4);
    }
  }
}

// Round 3
// 169.372 us; speedup vs baseline: 1.5449x; 1.3015x over previous
//
#include <hip/hip_runtime.h>
#include <stdint.h>

#define MDIM 1024
#define NDIM 2048
#define KDIM 2048
#define BETAC 0.9f
#define LAMC 1e-4f

typedef __attribute__((ext_vector_type(4))) float f32x4;
typedef __attribute__((ext_vector_type(8))) short s16x8;

typedef __attribute__((address_space(3))) unsigned int as3_u32;
typedef __attribute__((address_space(1))) unsigned int as1_u32;

__device__ __forceinline__ void gload_lds16(const void* g, const void* l) {
  __builtin_amdgcn_global_load_lds((const as1_u32*)(uintptr_t)g,
                                   (as3_u32*)(unsigned int)(uintptr_t)l, 16, 0, 0);
}

__device__ __forceinline__ unsigned short f2bf(float f) {
  union { float f; unsigned u; } x; x.f = f;
  unsigned r = x.u + 0x7fffu + ((x.u >> 16) & 1u);
  return (unsigned short)(r >> 16);
}

// ---------------- both weight transposes in one launch: WT[n][k] = bf16(W[k][n]) ----------------
__global__ __launch_bounds__(256) void transpose_cvt2_kernel(const float* __restrict__ Wz,
                                                             const float* __restrict__ Wx,
                                                             unsigned short* __restrict__ WzT,
                                                             unsigned short* __restrict__ WxT) {
  const float* W = blockIdx.z ? Wx : Wz;
  unsigned short* WT = blockIdx.z ? WxT : WzT;
  __shared__ float tile[32][33];
  const int tx = threadIdx.x, ty = threadIdx.y;
  const int col = blockIdx.x * 32 + tx;
  const int row0 = blockIdx.y * 32 + ty;
#pragma unroll
  for (int j = 0; j < 32; j += 8)
    tile[ty + j][tx] = W[(size_t)(row0 + j) * NDIM + col];
  __syncthreads();
  const int ocol = blockIdx.y * 32 + tx;
  const int orow0 = blockIdx.x * 32 + ty;
#pragma unroll
  for (int j = 0; j < 32; j += 8)
    WT[(size_t)(orow0 + j) * KDIM + ocol] = f2bf(tile[tx][ty + j]);
}

// ---------------- f32 -> bf16 elementwise ----------------
__global__ __launch_bounds__(256) void cvt_bf16_kernel(const float* __restrict__ in,
                                                       unsigned short* __restrict__ out, int n4) {
  int i = blockIdx.x * blockDim.x + threadIdx.x;
  if (i >= n4) return;
  f32x4 v = ((const f32x4*)in)[i];
  ushort4 o;
  o.x = f2bf(v[0]); o.y = f2bf(v[1]); o.z = f2bf(v[2]); o.w = f2bf(v[3]);
  ((ushort4*)out)[i] = o;
}

// ---------------- split-K GEMM: P[kz] = A(bf16 MxK_half) * BT(bf16 NxK_half)^T ----------------
// BM=64 BN=128 BK=64, KSPLIT=2 (blockIdx.z), 256 threads (4 waves of 32x64).
// LDS 48KB double-buffered -> 2 blocks/CU resident (grid 512), raw f32 partial output.
__global__ __launch_bounds__(256) void gemm_split_kernel(const unsigned short* __restrict__ A,
                                                         const unsigned short* __restrict__ BT,
                                                         float* __restrict__ P0,
                                                         float* __restrict__ P1) {
  __shared__ short As[2][64 * 64];    // 16 KB
  __shared__ short Bs[2][128 * 64];   // 32 KB

  const int tid = threadIdx.x;
  const int l = tid & 63;
  const int w = tid >> 6;
  const int wr = w >> 1, wc = w & 1;
  const int row0 = blockIdx.y * 64;
  const int col0 = blockIdx.x * 128;
  const int kbase = blockIdx.z * (KDIM / 2);
  const int lrow = l & 15;
  const int lk8 = (l >> 4) * 8;
  const int wuni = (tid & ~63) * 8;  // wave-uniform LDS element base

  f32x4 acc[2][4];
#pragma unroll
  for (int mi = 0; mi < 2; mi++)
#pragma unroll
    for (int ni = 0; ni < 4; ni++) acc[mi][ni] = f32x4{0.f, 0.f, 0.f, 0.f};

  // stage one BK=64 tile: A 64x64 (512 slots of 16B), B 128x64 (1024 slots)
  // slot u -> row r=u>>3, chunk c=((u&7)^(r&7))*8 (pre-swizzled source, linear LDS dest)
  auto stage = [&](int k0, int buf) {
#pragma unroll
    for (int p = 0; p < 2; p++) {
      int u = p * 256 + tid;
      int r = u >> 3;
      int c = ((u & 7) ^ (r & 7)) * 8;
      const unsigned short* src = A + (size_t)(row0 + r) * KDIM + k0 + c;
      const short* dst = &As[buf][p * 2048 + wuni];
      gload_lds16(src, dst);
    }
#pragma unroll
    for (int p = 0; p < 4; p++) {
      int u = p * 256 + tid;
      int r = u >> 3;
      int c = ((u & 7) ^ (r & 7)) * 8;
      const unsigned short* src = BT + (size_t)(col0 + r) * KDIM + k0 + c;
      const short* dst = &Bs[buf][p * 2048 + wuni];
      gload_lds16(src, dst);
    }
  };

  constexpr int NT = (KDIM / 2) / 64;  // 16
  stage(kbase, 0);
  asm volatile("s_waitcnt vmcnt(0)" ::: "memory");
  __syncthreads();

  for (int t = 0; t < NT; ++t) {
    const int cur = t & 1;
    if (t + 1 < NT) stage(kbase + (t + 1) * 64, cur ^ 1);
#pragma unroll
    for (int ks = 0; ks < 2; ++ks) {
      const int kk = ks * 32 + lk8;
      s16x8 a[2], b[4];
#pragma unroll
      for (int mi = 0; mi < 2; mi++) {
        int rr = wr * 32 + mi * 16 + lrow;
        int sidx = (rr * 64 + kk) ^ ((rr & 7) << 3);
        a[mi] = *(const s16x8*)(&As[cur][sidx]);
      }
#pragma unroll
      for (int ni = 0; ni < 4; ni++) {
        int rr = wc * 64 + ni * 16 + lrow;
        int sidx = (rr * 64 + kk) ^ ((rr & 7) << 3);
        b[ni] = *(const s16x8*)(&Bs[cur][sidx]);
      }
#pragma unroll
      for (int mi = 0; mi < 2; mi++)
#pragma unroll
        for (int ni = 0; ni < 4; ni++)
          acc[mi][ni] = __builtin_amdgcn_mfma_f32_16x16x32_bf16(a[mi], b[ni], acc[mi][ni], 0, 0, 0);
    }
    asm volatile("s_waitcnt vmcnt(0)" ::: "memory");
    __syncthreads();
  }

  float* __restrict__ P = blockIdx.z ? P1 : P0;
#pragma unroll
  for (int mi = 0; mi < 2; mi++) {
#pragma unroll
    for (int ni = 0; ni < 4; ni++) {
      const int col = col0 + wc * 64 + ni * 16 + lrow;
      const int rbase = row0 + wr * 32 + mi * 16 + (l >> 4) * 4;
#pragma unroll
      for (int j = 0; j < 4; j++)
        P[(size_t)(rbase + j) * NDIM + col] = acc[mi][ni][j];
    }
  }
}

// ---------------- fused per-row epilogue: combine partials + g + gamma + update ----------------
// MODE 0: xproj = P0+P1+bias; z1 = 0.9*tanh(xproj); writes xproj, z1, zb
// MODE 1: g = tanh(P0+P1+xproj) - z; z2 = z + 0.9g; writes g, z2, zb
// MODE 2: g, gamma(row), anderson update; writes g, znew, zb
// MODE 3: g, gamma(row), anderson update; writes d_out only
template <int MODE>
__global__ __launch_bounds__(256) void rowfused_kernel(const float* __restrict__ P0,
                                                       const float* __restrict__ P1,
                                                       const float* __restrict__ xp_or_bias,
                                                       const float* __restrict__ z,
                                                       const float* __restrict__ zp,
                                                       const float* __restrict__ gp,
                                                       float* __restrict__ gout,
                                                       float* __restrict__ zout,
                                                       unsigned short* __restrict__ zbout,
                                                       float* __restrict__ xpout) {
  const int row = blockIdx.x;
  const int tid = threadIdx.x;
  const size_t b4 = (size_t)row * (NDIM / 4);
  __shared__ float sn[4], sd[4];
  __shared__ float sga;

  int vi[2] = {tid, tid + 256};
  f32x4 gv[2], znv[2], zv[2], zpv[2], gpv[2];
  float num = 0.f, den = 0.f;

#pragma unroll
  for (int h = 0; h < 2; h++) {
    const size_t q = b4 + vi[h];
    f32x4 p0 = ((const f32x4*)P0)[q];
    f32x4 p1 = ((const f32x4*)P1)[q];
    f32x4 xb;
    if (MODE == 0) xb = ((const f32x4*)xp_or_bias)[vi[h]];   // bias (row-invariant)
    else xb = ((const f32x4*)xp_or_bias)[q];                 // xproj
    if (MODE != 0) zv[h] = ((const f32x4*)z)[q];
    if (MODE >= 2) {
      zpv[h] = ((const f32x4*)zp)[q];
      gpv[h] = ((const f32x4*)gp)[q];
    }
#pragma unroll
    for (int j = 0; j < 4; j++) {
      const float s = p0[j] + p1[j] + xb[j];
      if (MODE == 0) {
        const float z1 = BETAC * tanhf(s);
        gv[h][j] = s;      // xproj value to store
        znv[h][j] = z1;
      } else {
        const float g = tanhf(s) - zv[h][j];
        gv[h][j] = g;
        if (MODE == 1) znv[h][j] = zv[h][j] + BETAC * g;
        else {
          const float dg = g - gpv[h][j];
          num += dg * g;
          den += dg * dg;
        }
      }
    }
  }

  if (MODE >= 2) {
#pragma unroll
    for (int off = 32; off > 0; off >>= 1) {
      num += __shfl_down(num, off);
      den += __shfl_down(den, off);
    }
    if ((tid & 63) == 0) { sn[tid >> 6] = num; sd[tid >> 6] = den; }
    __syncthreads();
    if (tid == 0)
      sga = (sn[0] + sn[1] + sn[2] + sn[3]) / (sd[0] + sd[1] + sd[2] + sd[3] + LAMC);
    __syncthreads();
    const float ga = sga;
#pragma unroll
    for (int h = 0; h < 2; h++)
#pragma unroll
      for (int j = 0; j < 4; j++)
        znv[h][j] = zv[h][j] + BETAC * gv[h][j]
                  - ga * ((zv[h][j] - zpv[h][j]) + BETAC * (gv[h][j] - gpv[h][j]));
  }

#pragma unroll
  for (int h = 0; h < 2; h++) {
    const size_t q = b4 + vi[h];
    if (MODE == 0) ((f32x4*)xpout)[q] = gv[h];
    if (MODE == 1 || MODE == 2) ((f32x4*)gout)[q] = gv[h];
    ((f32x4*)zout)[q] = znv[h];
    if (MODE != 3) {
      ushort4 o;
      o.x = f2bf(znv[h][0]); o.y = f2bf(znv[h][1]);
      o.z = f2bf(znv[h][2]); o.w = f2bf(znv[h][3]);
      ((ushort4*)zbout)[q] = o;
    }
  }
}

extern "C" void kernel_launch(void* const* d_in, const int* in_sizes, int n_in,
                              void* d_out, int out_size, void* d_ws, size_t ws_size,
                              hipStream_t stream) {
  const float* x = (const float*)d_in[0];
  const float* Wz = (const float*)d_in[1];
  const float* Wx = (const float*)d_in[2];
  const float* bias = (const float*)d_in[3];

  const size_t MN = (size_t)MDIM * NDIM;
  const size_t KN = (size_t)KDIM * NDIM;
  char* ws = (char*)d_ws;
  size_t off = 0;
  auto alloc = [&](size_t bytes) -> void* {
    void* p = ws + off;
    off += (bytes + 255) & ~(size_t)255;
    return p;
  };
  unsigned short* WzT = (unsigned short*)alloc(KN * 2);
  unsigned short* WxT = (unsigned short*)alloc(KN * 2);
  unsigned short* xb = (unsigned short*)alloc(MN * 2);
  float* xproj = (float*)alloc(MN * 4);
  float* zA = (float*)alloc(MN * 4);
  float* zB = (float*)alloc(MN * 4);
  float* gA = (float*)alloc(MN * 4);
  float* gB = (float*)alloc(MN * 4);
  unsigned short* zb16 = (unsigned short*)alloc(MN * 2);
  float* P0 = (float*)alloc(MN * 4);
  float* P1 = (float*)alloc(MN * 4);
  (void)ws_size;

  const int n4 = (int)(MN / 4);
  const dim3 tb(32, 8);
  const dim3 tgrid(NDIM / 32, KDIM / 32, 2);
  const dim3 ggrid(NDIM / 128, MDIM / 64, 2);
  const int ewblocks = n4 / 256;

  transpose_cvt2_kernel<<<tgrid, tb, 0, stream>>>(Wz, Wx, WzT, WxT);
  cvt_bf16_kernel<<<ewblocks, 256, 0, stream>>>(x, xb, n4);

  // iter 0: x_proj = x@Wx + b ; z1 = 0.9*tanh(x_proj)
  gemm_split_kernel<<<ggrid, 256, 0, stream>>>(xb, WxT, P0, P1);
  rowfused_kernel<0><<<MDIM, 256, 0, stream>>>(P0, P1, bias, nullptr, nullptr, nullptr,
                                               nullptr, zA, zb16, xproj);

  float* zc = zA;
  float* zp = zB;
  float* gc = gA;
  float* gp = gB;

  // iter 1: simple update
  gemm_split_kernel<<<ggrid, 256, 0, stream>>>(zb16, WzT, P0, P1);
  rowfused_kernel<1><<<MDIM, 256, 0, stream>>>(P0, P1, xproj, zc, nullptr, nullptr,
                                               gc, zp, zb16, nullptr);
  { float* t = zc; zc = zp; zp = t; }   // zc=z2, zp=z1
  { float* t = gc; gc = gp; gp = t; }   // gp=g1

  // iters 2..4: anderson updates
  for (int it = 2; it < 5; ++it) {
    gemm_split_kernel<<<ggrid, 256, 0, stream>>>(zb16, WzT, P0, P1);
    rowfused_kernel<2><<<MDIM, 256, 0, stream>>>(P0, P1, xproj, zc, zp, gp,
                                                 gc, zp, zb16, nullptr);
    { float* t = zc; zc = zp; zp = t; }
    { float* t = gc; gc = gp; gp = t; }
  }

  // iter 5: final anderson update straight to d_out
  gemm_split_kernel<<<ggrid, 256, 0, stream>>>(zb16, WzT, P0, P1);
  rowfused_kernel<3><<<MDIM, 256, 0, stream>>>(P0, P1, xproj, zc, zp, gp,
                                               nullptr, (float*)d_out, nullptr, nullptr);
}